// Round 11
// baseline (363.121 us; speedup 1.0000x reference)
//
#include <hip/hip_runtime.h>
#include <stdint.h>

#define Bc   2
#define Lc   1024
#define Pc   1024
#define Tc   2048
#define HIDc 2048
#define NHc  32
#define NKVc 8
#define Dc   64

typedef __bf16 bf16x8 __attribute__((ext_vector_type(8)));
typedef float f32x4 __attribute__((ext_vector_type(4)));

__device__ inline unsigned short f2bf(float f) {
  union { float f; uint32_t u; } v; v.f = f;
  uint32_t u = v.u;
  uint32_t r = (u + 0x7fffu + ((u >> 16) & 1u)) >> 16;
  return (unsigned short)r;
}
// cheap round-half-up bf16 (values >= 0 only)
__device__ inline unsigned short f2bf_rhu(float f) {
  union { float f; uint32_t u; } v; v.f = f;
  return (unsigned short)((v.u + 0x8000u) >> 16);
}
__device__ inline float bf2f(unsigned short h) {
  union { uint32_t u; float f; } v; v.u = ((uint32_t)h) << 16;
  return v.f;
}
__device__ inline float exp2_fast(float x) {
#if defined(__has_builtin)
#if __has_builtin(__builtin_amdgcn_exp2f)
  return __builtin_amdgcn_exp2f(x);
#else
  return exp2f(x);
#endif
#else
  return exp2f(x);
#endif
}

typedef const __attribute__((address_space(1))) unsigned int* gas1_t;
typedef __attribute__((address_space(3))) unsigned int* las3_t;
__device__ inline void gload_lds16(const void* g, void* l) {
  __builtin_amdgcn_global_load_lds((gas1_t)g, (las3_t)l, 16, 0, 0);
}

// ---- fused prep: weight transpose+cast, x cast, past-KV cast (3 paths, 1 dispatch) ----
// grid (368, 32) x (32,8):
//   bx <160: transpose Wq/Wk/Wv/Wo -> WqkvT/WoT
//   bx <288: cast x -> xb
//   else   : past_k cast -> Kc[t<1024], past_v cast+transpose -> Vc[t<1024]
__global__ void prep_kernel(const float* __restrict__ x, unsigned short* __restrict__ xb,
                            const float* __restrict__ Wq, const float* __restrict__ Wk,
                            const float* __restrict__ Wv, const float* __restrict__ Wo,
                            const float* __restrict__ past_k, const float* __restrict__ past_v,
                            unsigned short* __restrict__ WqkvT, unsigned short* __restrict__ WoT,
                            unsigned short* __restrict__ Kc, unsigned short* __restrict__ Vc) {
  int bx = blockIdx.x;
  int tid = threadIdx.y * 32 + threadIdx.x;
  if (bx >= 288) {
    int vx = (bx - 288) * 32 + blockIdx.y;  // 0..2559
    if (vx < 2048) {
      // past_k: 16 bh x 1024 t x 32 d-pairs
      int idx = vx * 256 + tid;
      int d = idx & 31;
      int t = (idx >> 5) & 1023;
      int bh = idx >> 15;
      size_t pb = ((size_t)bh * 1024 + t) * 64 + d;
      size_t ob = ((size_t)bh * 2048 + t) * 64 + d;
      Kc[ob] = f2bf(past_k[pb]);
      Kc[ob + 32] = f2bf(past_k[pb + 32]);
    } else {
      // past_v transpose: 16 bh x 32 t-slices of 32
      __shared__ unsigned short sv[32][72];
      int vxx = vx - 2048;  // 0..511
      int t0 = (vxx & 31) * 32;
      int bh = vxx >> 5;
#pragma unroll
      for (int i = 0; i < 8; ++i) {
        int e = tid + 256 * i;
        int tl = e >> 6, d = e & 63;
        sv[tl][d] = f2bf(past_v[((size_t)bh * 1024 + t0 + tl) * 64 + d]);
      }
      __syncthreads();
#pragma unroll
      for (int i = 0; i < 8; ++i) {
        int e = tid + 256 * i;
        int d = e >> 5, tl = e & 31;
        Vc[((size_t)bh * 64 + d) * 2048 + t0 + tl] = sv[tl][d];
      }
    }
    return;
  }
  if (bx >= 160) {
    int blk = (bx - 160) * 32 + blockIdx.y;  // 0..4095
    int i = (blk * 256 + tid) * 4;
    float4 v = *(const float4*)(x + i);
    ushort4 o;
    o.x = f2bf(v.x); o.y = f2bf(v.y); o.z = f2bf(v.z); o.w = f2bf(v.w);
    *(ushort4*)(xb + i) = o;
    return;
  }
  __shared__ float s[32][65];  // [n-local][k-local]
  int k0 = blockIdx.y * 64;
  const float* W;
  unsigned short* dst;
  int N, n0, drow;
  if (bx < 64)       { W = Wq; dst = WqkvT; N = 2048; n0 = bx * 32;        drow = n0; }
  else if (bx < 80)  { W = Wk; dst = WqkvT; N = 512;  n0 = (bx - 64) * 32; drow = 2048 + n0; }
  else if (bx < 96)  { W = Wv; dst = WqkvT; N = 512;  n0 = (bx - 80) * 32; drow = 2560 + n0; }
  else               { W = Wo; dst = WoT;   N = 2048; n0 = (bx - 96) * 32; drow = n0; }
  int tx = threadIdx.x, ty = threadIdx.y;  // (32,8)
#pragma unroll
  for (int j = 0; j < 8; ++j) {
    int r = ty + j * 8;
    s[tx][r] = W[(size_t)(k0 + r) * N + n0 + tx];
  }
  __syncthreads();
#pragma unroll
  for (int j = 0; j < 4; ++j) {
    int rr = ty + j * 8;
    float2 v = *(float2*)&s[rr][2 * tx];
    ushort2 o;
    o.x = f2bf(v.x); o.y = f2bf(v.y);
    *(ushort2*)(dst + (size_t)(drow + rr) * 2048 + k0 + 2 * tx) = o;
  }
}

// ---------------- GEMM: 64x128 tile, XCD swizzle, 3-deep 1-barrier pipeline ----------------
// EPI==0: plain fp32 store (out-proj). EPI==1: fused qkv epilogue — q-cols get
// RoPE + 0.125*log2e scale -> qkvb; k-cols get RoPE -> Kc[t>=1024]; v-cols get
// transposed packed store -> Vc[t>=1024]. C-layout lane holds (d, d+32) of one
// 64-aligned head (ni and ni+2), so RoPE pairing is lane-local; V's 4 row-
// consecutive acc values pack into one 8B store in the [d][t] cache.
template <int TM, int NBX, int EPI>
__global__ __launch_bounds__(256, 3) void gemm_kernel(
    const unsigned short* __restrict__ A, const unsigned short* __restrict__ BT,
    const float* __restrict__ bq, const float* __restrict__ bk, const float* __restrict__ bv,
    const float* __restrict__ cosb, const float* __restrict__ sinb,
    unsigned short* __restrict__ Qout, unsigned short* __restrict__ Kc,
    unsigned short* __restrict__ Vc, float* __restrict__ Fout, int N) {
  const int K = 2048;
  const int MI = TM / 32;
  __shared__ unsigned short sA[4][TM * 32];
  __shared__ unsigned short sB[4][128 * 32];

  const int f = blockIdx.x;
  const int xcd = f & 7;
  const int idx = f >> 3;
  const int nloc = idx % NBX;
  const int mblk = idx / NBX;
  const int m0 = mblk * TM;
  const int n0 = (xcd * NBX + nloc) * 128;

  const int tid = threadIdx.x;
  const int lane = tid & 63, w = tid >> 6;
  const int l15 = lane & 15, quad = lane >> 4;
  const int wm = (w & 1) * (TM / 2), wn = (w >> 1) * 64;

  f32x4 acc[MI][4];
#pragma unroll
  for (int i = 0; i < MI; ++i)
#pragma unroll
    for (int j = 0; j < 4; ++j) {
      f32x4 z = {0.f, 0.f, 0.f, 0.f};
      acc[i][j] = z;
    }

  const unsigned short* ga = A + (size_t)(m0 + (tid >> 2)) * K + (tid & 3) * 8;
  const unsigned short* gb = BT + (size_t)(n0 + (tid >> 2)) * K + (tid & 3) * 8;

  auto issue = [&](int tile, int buf) {
    int kb = tile * 32;
#pragma unroll
    for (int i = 0; i < TM / 64; ++i)
      gload_lds16(ga + (size_t)(i * 64) * K + kb, &sA[buf][i * 64 * 32 + tid * 8]);
    gload_lds16(gb + kb, &sB[buf][tid * 8]);
    gload_lds16(gb + (size_t)64 * K + kb, &sB[buf][64 * 32 + tid * 8]);
  };

  issue(0, 0);
  issue(1, 1);
  issue(2, 2);
  for (int t = 0; t < 64; ++t) {
    asm volatile("s_waitcnt vmcnt(6)" ::: "memory");
    __builtin_amdgcn_s_barrier();
    int tn = t + 3;
    if (tn > 63) tn = 63;
    issue(tn, (t + 3) & 3);
    const unsigned short* bA = sA[t & 3];
    const unsigned short* bB = sB[t & 3];
    bf16x8 af[MI], bfr[4];
#pragma unroll
    for (int i = 0; i < MI; ++i)
      af[i] = *(const bf16x8*)(bA + (wm + i * 16 + l15) * 32 + quad * 8);
#pragma unroll
    for (int i = 0; i < 4; ++i)
      bfr[i] = *(const bf16x8*)(bB + (wn + i * 16 + l15) * 32 + quad * 8);
#pragma unroll
    for (int mi = 0; mi < MI; ++mi)
#pragma unroll
      for (int ni = 0; ni < 4; ++ni)
        acc[mi][ni] = __builtin_amdgcn_mfma_f32_16x16x32_bf16(af[mi], bfr[ni], acc[mi][ni], 0, 0, 0);
  }

  if (EPI == 0) {
#pragma unroll
    for (int mi = 0; mi < MI; ++mi)
#pragma unroll
      for (int ni = 0; ni < 4; ++ni) {
        int col = n0 + wn + ni * 16 + l15;
#pragma unroll
        for (int r = 0; r < 4; ++r) {
          int row = m0 + wm + mi * 16 + quad * 4 + r;
          Fout[(size_t)row * N + col] = acc[mi][ni][r];
        }
      }
  } else {
    const int colbase = n0 + wn;  // multiple of 64 -> exactly one head
    if (colbase < 2048) {
      const float SC = 0.125f * 1.44269504f;
#pragma unroll
      for (int mi = 0; mi < MI; ++mi)
#pragma unroll
        for (int r = 0; r < 4; ++r) {
          int row = m0 + wm + mi * 16 + quad * 4 + r;
          int l = row & 1023;
#pragma unroll
          for (int ni = 0; ni < 2; ++ni) {
            int d0 = ni * 16 + l15;
            float c = cosb[l * 64 + d0] * SC;
            float s = sinb[l * 64 + d0] * SC;
            float qlo = acc[mi][ni][r] + bq[colbase + d0];
            float qhi = acc[mi][ni + 2][r] + bq[colbase + d0 + 32];
            unsigned short* dst = Qout + (size_t)row * 3072 + colbase + d0;
            dst[0] = f2bf(qlo * c - qhi * s);
            dst[32] = f2bf(qhi * c + qlo * s);
          }
        }
    } else if (colbase < 2560) {
      int hk = (colbase - 2048) >> 6;
#pragma unroll
      for (int mi = 0; mi < MI; ++mi)
#pragma unroll
        for (int r = 0; r < 4; ++r) {
          int row = m0 + wm + mi * 16 + quad * 4 + r;
          int b = row >> 10, l = row & 1023;
          size_t base = ((size_t)(b * 8 + hk) * 2048 + 1024 + l) * 64;
#pragma unroll
          for (int ni = 0; ni < 2; ++ni) {
            int d0 = ni * 16 + l15;
            float c = cosb[l * 64 + d0];
            float s = sinb[l * 64 + d0];
            float klo = acc[mi][ni][r] + bk[colbase - 2048 + d0];
            float khi = acc[mi][ni + 2][r] + bk[colbase - 2048 + d0 + 32];
            Kc[base + d0] = f2bf(klo * c - khi * s);
            Kc[base + d0 + 32] = f2bf(khi * c + klo * s);
          }
        }
    } else {
      int hk = (colbase - 2560) >> 6;
#pragma unroll
      for (int mi = 0; mi < MI; ++mi) {
        int row0 = m0 + wm + mi * 16 + quad * 4;
        int b = row0 >> 10, l0 = row0 & 1023;
#pragma unroll
        for (int ni = 0; ni < 4; ++ni) {
          int d = ni * 16 + l15;
          float bvv = bv[colbase - 2560 + d];
          uint2 pk;
          pk.x = (uint32_t)f2bf(acc[mi][ni][0] + bvv) | ((uint32_t)f2bf(acc[mi][ni][1] + bvv) << 16);
          pk.y = (uint32_t)f2bf(acc[mi][ni][2] + bvv) | ((uint32_t)f2bf(acc[mi][ni][3] + bvv) << 16);
          *(uint2*)(Vc + ((size_t)(b * 8 + hk) * 64 + d) * 2048 + 1024 + l0) = pk;
        }
      }
    }
  }
}

// ---------------- flash attention v8: v6 body, pre-roped q, LSTR 68 (3 blocks/CU) ----------
// Block = (b, hk, 32-row q-chunk), 4 waves, wave w owns head hk*4+w; GQA-shared
// K/V tiles staged once per block into LDS; 1 barrier/tile. q arrives pre-roped
// and pre-scaled (0.125*log2e folded) from the qkv GEMM epilogue -> prologue is
// two b128 loads. LSTR=68: 52224 B LDS -> 3 blocks/CU (was 55296 -> 2); stride
// 68 elems = 34 dwords == 2 mod 32 keeps wave b128 access uniformly 8/bank.
#define LSTR 68
__global__ __launch_bounds__(256, 2) void attn_kernel(
    const unsigned short* __restrict__ qkv,  // [B*L][3072] (q cols pre-roped*SC)
    const unsigned short* __restrict__ Kc,   // [B][NKV][T][D]
    const unsigned short* __restrict__ Vc,   // [B][NKV][D][T]
    unsigned short* __restrict__ O) {        // [B*L][2048]
  __shared__ unsigned short sK[2][64 * LSTR];
  __shared__ unsigned short sV[2][64 * LSTR];
  __shared__ unsigned short sPs[4][32 * LSTR];

  int flat = blockIdx.x;                          // 0..511
  int pair = (flat & 7) * 2 + ((flat >> 3) & 1);  // b*8+hk, XCD-pinned
  int b = pair >> 3, hk = pair & 7;
  int qt = flat >> 4;                             // 0..31
  int q0 = qt * 32;

  const int tid = threadIdx.x;
  const int lane = tid & 63, w = tid >> 6;
  const int l15 = lane & 15, quad = lane >> 4;
  const int h = hk * 4 + w;

  unsigned short* sP = sPs[w];

  // ---- Q fragments: plain loads (RoPE+scale already applied) ----
  bf16x8 qf[2][2];
#pragma unroll
  for (int mi = 0; mi < 2; ++mi) {
    int row = q0 + mi * 16 + l15;
    const unsigned short* qrow = qkv + (size_t)(b * 1024 + row) * 3072 + h * 64;
    qf[mi][0] = *(const bf16x8*)(qrow + quad * 8);
    qf[mi][1] = *(const bf16x8*)(qrow + 32 + quad * 8);
  }

  const unsigned short* Kb = Kc + ((size_t)b * 8 + hk) * (2048 * 64);
  const unsigned short* Vb = Vc + ((size_t)b * 8 + hk) * (64 * 2048);

  const int sr = tid >> 3;
  const int sc = (tid & 7) * 8;

  uint4 kreg0, kreg1, vreg0, vreg1;
  auto issueLoads = [&](int t0) {
    kreg0 = *(const uint4*)(Kb + (size_t)(t0 + sr) * 64 + sc);
    kreg1 = *(const uint4*)(Kb + (size_t)(t0 + sr + 32) * 64 + sc);
    vreg0 = *(const uint4*)(Vb + (size_t)sr * 2048 + t0 + sc);
    vreg1 = *(const uint4*)(Vb + (size_t)(sr + 32) * 2048 + t0 + sc);
  };
  auto writeStage = [&](int buf) {
    *(uint4*)(&sK[buf][sr * LSTR + sc]) = kreg0;
    *(uint4*)(&sK[buf][(sr + 32) * LSTR + sc]) = kreg1;
    *(uint4*)(&sV[buf][sr * LSTR + sc]) = vreg0;
    *(uint4*)(&sV[buf][(sr + 32) * LSTR + sc]) = vreg1;
  };

  f32x4 oacc[2][4];
  float lsum[2][4];
#pragma unroll
  for (int mi = 0; mi < 2; ++mi) {
#pragma unroll
    for (int nd = 0; nd < 4; ++nd) {
      f32x4 z = {0.f, 0.f, 0.f, 0.f};
      oacc[mi][nd] = z;
    }
#pragma unroll
    for (int r = 0; r < 4; ++r) lsum[mi][r] = 0.f;
  }

  const int ntile = (q0 + 32 + 1024 + 63) >> 6;  // 17..32

  issueLoads(0);
  writeStage(0);
  __syncthreads();

  for (int kt = 0; kt < ntile; ++kt) {
    int t0n = (kt + 1) * 64;
    if (t0n > 1984) t0n = 1984;
    issueLoads(t0n);

    const int t0 = kt * 64;
    const int buf = kt & 1;
    const unsigned short* bK = sK[buf];
    const unsigned short* bV = sV[buf];

    f32x4 sacc[2][4];
#pragma unroll
    for (int mi = 0; mi < 2; ++mi)
#pragma unroll
      for (int nt = 0; nt < 4; ++nt) {
        f32x4 z = {0.f, 0.f, 0.f, 0.f};
        sacc[mi][nt] = z;
      }
#pragma unroll
    for (int ks = 0; ks < 2; ++ks)
#pragma unroll
      for (int nt = 0; nt < 4; ++nt) {
        bf16x8 kf = *(const bf16x8*)(bK + (nt * 16 + l15) * LSTR + ks * 32 + quad * 8);
#pragma unroll
        for (int mi = 0; mi < 2; ++mi)
          sacc[mi][nt] = __builtin_amdgcn_mfma_f32_16x16x32_bf16(qf[mi][ks], kf, sacc[mi][nt], 0, 0, 0);
      }

    const bool diag = (t0 + 63 > q0 + Pc);
    if (!diag) {
#pragma unroll
      for (int mi = 0; mi < 2; ++mi)
#pragma unroll
        for (int nt = 0; nt < 4; ++nt)
#pragma unroll
          for (int r = 0; r < 4; ++r) {
            float pv = exp2_fast(sacc[mi][nt][r]);
            lsum[mi][r] += pv;
            sP[(mi * 16 + quad * 4 + r) * LSTR + nt * 16 + l15] = f2bf_rhu(pv);
          }
    } else {
#pragma unroll
      for (int mi = 0; mi < 2; ++mi)
#pragma unroll
        for (int nt = 0; nt < 4; ++nt)
#pragma unroll
          for (int r = 0; r < 4; ++r) {
            int tg = t0 + nt * 16 + l15;
            int rg = q0 + mi * 16 + quad * 4 + r;
            float pv = (tg > rg + Pc) ? 0.f : exp2_fast(sacc[mi][nt][r]);
            lsum[mi][r] += pv;
            sP[(mi * 16 + quad * 4 + r) * LSTR + nt * 16 + l15] = f2bf_rhu(pv);
          }
    }
    asm volatile("s_waitcnt lgkmcnt(0)" ::: "memory");

    bf16x8 vf[2][4];
#pragma unroll
    for (int tk = 0; tk < 2; ++tk)
#pragma unroll
      for (int nd = 0; nd < 4; ++nd)
        vf[tk][nd] = *(const bf16x8*)(bV + (nd * 16 + l15) * LSTR + tk * 32 + quad * 8);
#pragma unroll
    for (int mi = 0; mi < 2; ++mi)
#pragma unroll
      for (int tk = 0; tk < 2; ++tk) {
        bf16x8 a = *(const bf16x8*)(sP + (mi * 16 + l15) * LSTR + tk * 32 + quad * 8);
#pragma unroll
        for (int nd = 0; nd < 4; ++nd)
          oacc[mi][nd] = __builtin_amdgcn_mfma_f32_16x16x32_bf16(a, vf[tk][nd], oacc[mi][nd], 0, 0, 0);
      }

    writeStage(buf ^ 1);
    __syncthreads();
  }

  float inv[2][4];
#pragma unroll
  for (int mi = 0; mi < 2; ++mi)
#pragma unroll
    for (int r = 0; r < 4; ++r) {
      float v = lsum[mi][r];
      v += __shfl_xor(v, 1);
      v += __shfl_xor(v, 2);
      v += __shfl_xor(v, 4);
      v += __shfl_xor(v, 8);
      inv[mi][r] = 1.f / v;
    }
#pragma unroll
  for (int mi = 0; mi < 2; ++mi)
#pragma unroll
    for (int nd = 0; nd < 4; ++nd) {
      int col = h * 64 + nd * 16 + l15;
#pragma unroll
      for (int r = 0; r < 4; ++r) {
        int row = b * 1024 + q0 + mi * 16 + quad * 4 + r;
        O[(size_t)row * 2048 + col] = f2bf(oacc[mi][nd][r] * inv[mi][r]);
      }
    }
}

extern "C" void kernel_launch(void* const* d_in, const int* in_sizes, int n_in,
                              void* d_out, int out_size, void* d_ws, size_t ws_size,
                              hipStream_t stream) {
  const float* x      = (const float*)d_in[0];
  const float* cosb   = (const float*)d_in[2];
  const float* sinb   = (const float*)d_in[3];
  const float* past_k = (const float*)d_in[4];
  const float* past_v = (const float*)d_in[5];
  const float* Wq     = (const float*)d_in[6];
  const float* bq     = (const float*)d_in[7];
  const float* Wk     = (const float*)d_in[8];
  const float* bk     = (const float*)d_in[9];
  const float* Wv     = (const float*)d_in[10];
  const float* bv     = (const float*)d_in[11];
  const float* Wo     = (const float*)d_in[12];
  float* out = (float*)d_out;

  char* ws = (char*)d_ws;
  unsigned short* xb    = (unsigned short*)(ws + ((size_t)0 << 20));   // 0-8 MB
  unsigned short* WqkvT = (unsigned short*)(ws + ((size_t)8 << 20));   // 8-20 MB
  unsigned short* WoT   = (unsigned short*)(ws + ((size_t)20 << 20));  // 20-28 MB
  unsigned short* qkvb  = (unsigned short*)(ws + ((size_t)28 << 20));  // 28-40 MB (q cols only)
  unsigned short* Kc    = (unsigned short*)(ws + ((size_t)40 << 20));  // 40-44 MB
  unsigned short* Vc    = (unsigned short*)(ws + ((size_t)44 << 20));  // 44-48 MB
  unsigned short* attno = (unsigned short*)(ws + ((size_t)48 << 20));  // 48-56 MB

  prep_kernel<<<dim3(368, 32), dim3(32, 8), 0, stream>>>(
      x, xb, Wq, Wk, Wv, Wo, past_k, past_v, WqkvT, WoT, Kc, Vc);

  // qkv GEMM + fused RoPE/KV-cache epilogue: 24 n-blocks (8 XCDs x 3) x 32 m
  gemm_kernel<64, 3, 1><<<768, 256, 0, stream>>>(
      xb, WqkvT, bq, bk, bv, cosb, sinb, qkvb, Kc, Vc, nullptr, 3072);

  attn_kernel<<<512, 256, 0, stream>>>(qkvb, Kc, Vc, attno);

  // out-proj: 16 n-blocks (8 XCDs x 2) x 32 m
  gemm_kernel<64, 2, 0><<<512, 256, 0, stream>>>(
      attno, WoT, nullptr, nullptr, nullptr, nullptr, nullptr, nullptr, nullptr, nullptr, out, 2048);
}